// Round 1
// baseline (649678.467 us; speedup 1.0000x reference)
//
#include <hip/hip_runtime.h>
#include <hip/hip_bf16.h>

#define TLEN 4096
#define HID  256
#define IN2  512
#define NB   64

__device__ __forceinline__ float sigmoidf_(float x){
    return 1.f/(1.f+__expf(-x));
}
__device__ __forceinline__ float tanhf_(float x){
    x = fminf(30.f, fmaxf(-30.f, x));
    float e = __expf(-2.f*x);
    return (1.f-e)/(1.f+e);
}

// One persistent workgroup per batch element. 16 waves * 64 lanes.
// lane = (k4, j): k4 = K-chunk (4-way split), j = output sub-index.
// wave w owns output neurons n = 16*w + j  (n in [0,256)).
// Register-resident weights per lane:
//   wr_[128]: Wr[k4*128 + i][n]   (K=512: comb=[x,h])
//   wz_[128]: Wz[k4*128 + i][n]
//   whx_[64]: Wh[k4*64  + i][n]   (x-part, K=256)
//   whh_[64]: Wh[256 + k4*64 + i][n] (r*h part, K=256)
template<int PASS>
__global__ __launch_bounds__(1024, 4)
void gru_pass(const int* __restrict__ tokens, const float* __restrict__ emb,
              const float* __restrict__ Wr, const float* __restrict__ br,
              const float* __restrict__ Wz, const float* __restrict__ bz,
              const float* __restrict__ Wh, const float* __restrict__ bh,
              const float* __restrict__ Wfc, const float* __restrict__ bfc,
              __hip_bfloat16* __restrict__ h0buf, float* __restrict__ out)
{
    __shared__ __align__(16) float s_comb[IN2];   // [x(256) | h(256)]
    __shared__ __align__(16) float s_rh[HID];     // r*h
    __shared__ int s_tok[TLEN];                   // pass-0 only

    const int b    = blockIdx.x;
    const int tid  = threadIdx.x;
    const int wave = tid >> 6;
    const int lane = tid & 63;
    const int k4   = lane >> 4;      // 0..3
    const int j    = lane & 15;      // 0..15
    const int n    = (wave << 4) | j;

    const float* WrL = Wr + PASS*IN2*HID;
    const float* WzL = Wz + PASS*IN2*HID;
    const float* WhL = Wh + PASS*IN2*HID;

    float wr_[128], wz_[128], whx_[64], whh_[64];
#pragma unroll
    for (int i=0;i<128;++i) wr_[i]  = WrL[(k4*128+i)*HID + n];
#pragma unroll
    for (int i=0;i<128;++i) wz_[i]  = WzL[(k4*128+i)*HID + n];
#pragma unroll
    for (int i=0;i<64;++i)  whx_[i] = WhL[(k4*64+i)*HID + n];
#pragma unroll
    for (int i=0;i<64;++i)  whh_[i] = WhL[(256 + k4*64+i)*HID + n];

    float biasr=0.f, biasz=0.f, biash=0.f, hreg=0.f, zreg=0.f, phx=0.f;
    if (k4==0){
        biasr = br[PASS*HID+n];
        biasz = bz[PASS*HID+n];
        biash = bh[PASS*HID+n];
    }

    if (PASS==0){
        for (int i=tid;i<TLEN;i+=1024) s_tok[i] = tokens[(size_t)b*TLEN + i];
    }
    __syncthreads();

    // x(t=0) and h=0
    if (tid < IN2){
        float v = 0.f;
        if (tid < HID){
            if (PASS==0){ int tk = s_tok[0]; v = emb[(size_t)tk*HID + tid]; }
            else        { v = __bfloat162float(h0buf[(size_t)b*TLEN*HID + tid]); }
        }
        s_comb[tid] = v;
    }
    __syncthreads();

#pragma unroll 1
    for (int t=0; t<TLEN; ++t){
        // ---- prefetch x(t+1) into registers (hidden under sub-A/B compute) ----
        float xnext = 0.f;
        if (t+1 < TLEN && tid < HID){
            if (PASS==0){ int tk = s_tok[t+1]; xnext = emb[(size_t)tk*HID + tid]; }
            else        { xnext = __bfloat162float(h0buf[((size_t)b*TLEN + (t+1))*HID + tid]); }
        }

        // ---- sub-step A: pre_r, pre_z over comb=[x,h]; pre_h x-part ----
        float accr=0.f, accz=0.f, acchx=0.f;
        {
            const float4* c4 = (const float4*)(s_comb + k4*128);
#pragma unroll
            for (int u=0;u<32;++u){
                float4 cv = c4[u];
                accr += wr_[4*u+0]*cv.x; accr += wr_[4*u+1]*cv.y;
                accr += wr_[4*u+2]*cv.z; accr += wr_[4*u+3]*cv.w;
                accz += wz_[4*u+0]*cv.x; accz += wz_[4*u+1]*cv.y;
                accz += wz_[4*u+2]*cv.z; accz += wz_[4*u+3]*cv.w;
            }
            const float4* x4p = (const float4*)(s_comb + k4*64);
#pragma unroll
            for (int u=0;u<16;++u){
                float4 cv = x4p[u];
                acchx += whx_[4*u+0]*cv.x; acchx += whx_[4*u+1]*cv.y;
                acchx += whx_[4*u+2]*cv.z; acchx += whx_[4*u+3]*cv.w;
            }
        }
        accr  += __shfl_xor(accr ,16); accr  += __shfl_xor(accr ,32);
        accz  += __shfl_xor(accz ,16); accz  += __shfl_xor(accz ,32);
        acchx += __shfl_xor(acchx,16); acchx += __shfl_xor(acchx,32);

        if (k4==0){
            float r = sigmoidf_(accr + biasr);
            zreg = sigmoidf_(accz + biasz);
            phx  = acchx;
            s_rh[n] = r * hreg;
        }
        __syncthreads();   // (1) rh ready

        // ---- sub-step B: pre_h h-part over r*h ----
        float acchh = 0.f;
        {
            const float4* r4 = (const float4*)(s_rh + k4*64);
#pragma unroll
            for (int u=0;u<16;++u){
                float4 cv = r4[u];
                acchh += whh_[4*u+0]*cv.x; acchh += whh_[4*u+1]*cv.y;
                acchh += whh_[4*u+2]*cv.z; acchh += whh_[4*u+3]*cv.w;
            }
        }
        acchh += __shfl_xor(acchh,16); acchh += __shfl_xor(acchh,32);

        if (k4==0){
            float ht = tanhf_(phx + acchh + biash);
            hreg = hreg + zreg*(ht - hreg);   // (1-z)h + z*ht
            s_comb[HID + n] = hreg;
        }
        if (t+1 < TLEN && tid < HID) s_comb[tid] = xnext;
        __syncthreads();   // (2) comb ready for next step

        // ---- pass-0: stream h0 history to ws (bf16), coalesced ----
        if (PASS==0){
            if (tid < 128){
                float a  = s_comb[HID + 2*tid];
                float b2 = s_comb[HID + 2*tid + 1];
                __hip_bfloat162 p;
                p.x = __float2bfloat16(a);
                p.y = __float2bfloat16(b2);
                *reinterpret_cast<__hip_bfloat162*>(h0buf + ((size_t)b*TLEN + t)*HID + 2*tid) = p;
            }
        }
    }

    // ---- pass-1: classification head on final h1 ----
    if (PASS==1 && wave==0){
        float p0=0.f, p1=0.f;
#pragma unroll
        for (int m=0;m<4;++m){
            int nn = lane + 64*m;
            float hv = s_comb[HID + nn];
            p0 += hv * Wfc[nn*2+0];
            p1 += hv * Wfc[nn*2+1];
        }
#pragma unroll
        for (int d=1; d<64; d<<=1){ p0 += __shfl_xor(p0,d); p1 += __shfl_xor(p1,d); }
        if (lane==0){ out[b*2+0] = p0 + bfc[0]; out[b*2+1] = p1 + bfc[1]; }
    }
}

extern "C" void kernel_launch(void* const* d_in, const int* in_sizes, int n_in,
                              void* d_out, int out_size, void* d_ws, size_t ws_size,
                              hipStream_t stream) {
    const int*   tokens = (const int*)  d_in[0];
    const float* emb    = (const float*)d_in[1];
    const float* Wr     = (const float*)d_in[2];
    const float* br     = (const float*)d_in[3];
    const float* Wz     = (const float*)d_in[4];
    const float* bz     = (const float*)d_in[5];
    const float* Wh     = (const float*)d_in[6];
    const float* bh     = (const float*)d_in[7];
    const float* Wfc    = (const float*)d_in[8];
    const float* bfc    = (const float*)d_in[9];
    float* out = (float*)d_out;
    __hip_bfloat16* h0buf = (__hip_bfloat16*)d_ws;  // needs 64*4096*256*2B = 128 MiB

    gru_pass<0><<<NB, 1024, 0, stream>>>(tokens, emb, Wr,br, Wz,bz, Wh,bh, Wfc,bfc, h0buf, out);
    gru_pass<1><<<NB, 1024, 0, stream>>>(tokens, emb, Wr,br, Wz,bz, Wh,bh, Wfc,bfc, h0buf, out);
}

// Round 2
// 12296.652 us; speedup vs baseline: 52.8338x; 52.8338x over previous
//
#include <hip/hip_runtime.h>
#include <hip/hip_bf16.h>
#include <hip/hip_fp16.h>
#include <stdint.h>

typedef _Float16 h2_t  __attribute__((ext_vector_type(2)));
typedef _Float16 f16x8 __attribute__((ext_vector_type(8)));
typedef float    f32x4 __attribute__((ext_vector_type(4)));

#define TSEQ 4096
#define HID  256
#define IN2  512
#define NB   64
#define CH   256      // steps per chunk (power of 2: grow>>8 = b)
#define NCH  16

// ---------------- prep: pack weights, transpose x-projection weights, emb->f16 ----------------
__global__ void prep_kernel(const float* __restrict__ Wr, const float* __restrict__ Wz,
                            const float* __restrict__ Wh, const float* __restrict__ emb,
                            uint32_t* __restrict__ wpack, __half* __restrict__ wxt,
                            __half* __restrict__ embf16)
{
    const long long S0 = 2LL*3*128*256;      // packed recurrent h-part weights
    const long long S1 = 2LL*768*256;        // WxT[L][o][k]
    const long long S2 = 32000LL*256;        // emb f16
    for (long long idx = (long long)blockIdx.x*256 + threadIdx.x; idx < S0+S1+S2;
         idx += (long long)gridDim.x*256) {
        if (idx < S0) {
            int n   = (int)(idx & 255);
            int kk2 = (int)((idx >> 8) & 127);
            int t   = (int)(idx >> 15);          // 0..5 = L*3+g
            int g = t % 3, L = t / 3;
            const float* Wsrc = (g==0?Wr:(g==1?Wz:Wh)) + (size_t)L*IN2*HID;
            h2_t p;
            p[0] = (_Float16)Wsrc[(256 + 2*kk2)*HID + n];
            p[1] = (_Float16)Wsrc[(257 + 2*kk2)*HID + n];
            wpack[idx] = __builtin_bit_cast(uint32_t, p);
        } else if (idx < S0+S1) {
            int i  = (int)(idx - S0);
            int k  = i & 255;
            int i2 = i >> 8;                     // 0..1535
            int o  = i2 % 768, L = i2 / 768;
            int g  = o >> 8,   n = o & 255;
            const float* Wsrc = (g==0?Wr:(g==1?Wz:Wh)) + (size_t)L*IN2*HID;
            wxt[i] = __float2half(Wsrc[k*HID + n]);   // WxT[L][o][k]
        } else {
            int i = (int)(idx - S0 - S1);
            embf16[i] = __float2half(emb[i]);
        }
    }
}

// ---------------- x-projection GEMM: proj[r][o] = A[r][:256] @ W*x  (f16 MFMA) ----------------
// A rows r = b*CH + tl. Layer0: A = embf16[tokens]; Layer1: A = h0chunk.
// Tile: BM=128 (4 waves x 32 rows), BN=64, K=256 staged in 2 halves of 128.
template<int LAYER>
__global__ __launch_bounds__(256) void gemm_proj(
    const int* __restrict__ tokens, const __half* __restrict__ embf16,
    const __half* __restrict__ h0chunk, const __half* __restrict__ wxt,
    __half* __restrict__ proj, int c)
{
    __shared__ uint4 Ald[128*17];   // stride 17 uint4 = 136 f16 (pad vs bank conflicts)
    __shared__ uint4 Bld[64*17];
    const int tid = threadIdx.x;
    const int mt = blockIdx.x, nt = blockIdx.y;
    const int w = tid >> 6, l = tid & 63, lr = l & 15, lk = l >> 4;
    f32x4 acc[2][4] = {};

#pragma unroll 1
    for (int kh = 0; kh < 2; ++kh) {
        if (kh) __syncthreads();
        // stage A half: 128 rows x 128 f16 (16 uint4/row)
#pragma unroll
        for (int it = 0; it < 8; ++it) {
            int idx = it*256 + tid;
            int row = idx >> 4, u4 = idx & 15;
            int grow = mt*128 + row;
            const __half* src;
            if (LAYER == 0) {
                int b = grow >> 8, tl = grow & (CH-1);
                int tok = tokens[(size_t)b*TSEQ + c*CH + tl];
                src = embf16 + (size_t)tok*HID;
            } else {
                src = h0chunk + (size_t)grow*HID;
            }
            Ald[row*17 + u4] = ((const uint4*)(src + kh*128))[u4];
        }
        // stage B half: 64 cols x 128 f16
#pragma unroll
        for (int it = 0; it < 4; ++it) {
            int idx = it*256 + tid;
            int col = idx >> 4, u4 = idx & 15;
            const __half* src = wxt + ((size_t)(LAYER*768 + nt*64 + col))*HID + kh*128;
            Bld[col*17 + u4] = ((const uint4*)src)[u4];
        }
        __syncthreads();
        const _Float16* A = (const _Float16*)Ald;
        const _Float16* B = (const _Float16*)Bld;
#pragma unroll
        for (int kb = 0; kb < 4; ++kb) {
            int k0 = kb*32;
            f16x8 af[2], bf[4];
#pragma unroll
            for (int fm = 0; fm < 2; ++fm) {
                int row = w*32 + fm*16 + lr;
                af[fm] = *(const f16x8*)(A + row*136 + k0 + lk*8);
            }
#pragma unroll
            for (int fn = 0; fn < 4; ++fn) {
                int col = fn*16 + lr;
                bf[fn] = *(const f16x8*)(B + col*136 + k0 + lk*8);
            }
#pragma unroll
            for (int fm = 0; fm < 2; ++fm)
#pragma unroll
                for (int fn = 0; fn < 4; ++fn)
                    acc[fm][fn] = __builtin_amdgcn_mfma_f32_16x16x32_f16(af[fm], bf[fn], acc[fm][fn], 0,0,0);
        }
    }
    // epilogue: C/D layout col=lane&15, row=(lane>>4)*4+q
#pragma unroll
    for (int fm = 0; fm < 2; ++fm)
#pragma unroll
        for (int fn = 0; fn < 4; ++fn)
#pragma unroll
            for (int q = 0; q < 4; ++q) {
                int row = mt*128 + w*32 + fm*16 + lk*4 + q;
                int col = nt*64 + fn*16 + lr;
                proj[(size_t)row*768 + col] = __float2half(acc[fm][fn][q]);
            }
}

// ---------------- recurrence: 1 block per batch elem, 512 thr, f16-packed weights in VGPRs ----
// thread (k = tid>>8, n = tid&255): neuron n, K-half k. 192 fdot2/thread/step.
template<int LAYER>
__global__ __launch_bounds__(512, 2) void rec_kernel(
    const uint32_t* __restrict__ wpack, const __half* __restrict__ proj,
    __half* __restrict__ h0chunk, float* __restrict__ hstate,
    const float* __restrict__ br, const float* __restrict__ bz, const float* __restrict__ bh,
    const float* __restrict__ Wfc, const float* __restrict__ bfc,
    float* __restrict__ out, int c)
{
    __shared__ __align__(16) _Float16 s_h[256];
    __shared__ __align__(16) _Float16 s_rh[256];
    __shared__ float s_redA[512];
    __shared__ float s_redB[256];

    const int b   = blockIdx.x;
    const int tid = threadIdx.x;
    const int k   = tid >> 8;     // wave-uniform (waves 0-3: k=0, 4-7: k=1)
    const int n   = tid & 255;

    h2_t wr_[64], wz_[64], wh_[64];
    {
        const uint32_t* p0 = wpack + ((size_t)((LAYER*3+0)*128 + 64*k))*256 + n;
        const uint32_t* p1 = wpack + ((size_t)((LAYER*3+1)*128 + 64*k))*256 + n;
        const uint32_t* p2 = wpack + ((size_t)((LAYER*3+2)*128 + 64*k))*256 + n;
#pragma unroll
        for (int i = 0; i < 64; ++i) wr_[i] = __builtin_bit_cast(h2_t, p0[i*256]);
#pragma unroll
        for (int i = 0; i < 64; ++i) wz_[i] = __builtin_bit_cast(h2_t, p1[i*256]);
#pragma unroll
        for (int i = 0; i < 64; ++i) wh_[i] = __builtin_bit_cast(h2_t, p2[i*256]);
    }

    float br_=0.f, bz_=0.f, bh_=0.f, h=0.f, z=0.f;
    if (!k) {
        br_ = br[LAYER*HID + n];
        bz_ = bz[LAYER*HID + n];
        bh_ = bh[LAYER*HID + n];
        h = (c == 0) ? 0.f : hstate[((size_t)LAYER*NB + b)*HID + n];
        s_h[n] = (_Float16)h;
    }
    __syncthreads();

    const __half* prow = proj + ((size_t)b*CH)*768;
    float pr=0.f, pz=0.f, ph=0.f;
    if (!k) {
        pr = __half2float(prow[n]);
        pz = __half2float(prow[256+n]);
        ph = __half2float(prow[512+n]);
    }

    const h2_t* h2p  = (const h2_t*)s_h;
    const h2_t* rh2p = (const h2_t*)s_rh;
    const int kb = 64*k;

#pragma unroll 1
    for (int tl = 0; tl < CH; ++tl) {
        // prefetch next step's x-projections (hidden under this step's compute)
        float prN=0.f, pzN=0.f, phN=0.f;
        if (!k && tl+1 < CH) {
            const __half* pnx = prow + (size_t)(tl+1)*768;
            prN = __half2float(pnx[n]);
            pzN = __half2float(pnx[256+n]);
            phN = __half2float(pnx[512+n]);
        }
        // phase A: r,z dots over h (K-half per thread), 2-way split accumulators
        float ar0=0.f, ar1=0.f, az0=0.f, az1=0.f;
#pragma unroll
        for (int i = 0; i < 32; ++i) {
            h2_t hv0 = h2p[kb+i], hv1 = h2p[kb+32+i];
            ar0 = __builtin_amdgcn_fdot2(wr_[i],    hv0, ar0, false);
            ar1 = __builtin_amdgcn_fdot2(wr_[32+i], hv1, ar1, false);
            az0 = __builtin_amdgcn_fdot2(wz_[i],    hv0, az0, false);
            az1 = __builtin_amdgcn_fdot2(wz_[32+i], hv1, az1, false);
        }
        if (k) { s_redA[n] = ar0+ar1; s_redA[256+n] = az0+az1; }
        __syncthreads();
        if (!k) {
            float prer = ar0+ar1 + s_redA[n]     + pr + br_;
            float prez = az0+az1 + s_redA[256+n] + pz + bz_;
            float r = 1.f/(1.f+__expf(-prer));
            z       = 1.f/(1.f+__expf(-prez));
            s_rh[n] = (_Float16)(r*h);
        }
        __syncthreads();
        // phase B: candidate dot over r*h
        float ah0=0.f, ah1=0.f;
#pragma unroll
        for (int i = 0; i < 32; ++i) {
            ah0 = __builtin_amdgcn_fdot2(wh_[i],    rh2p[kb+i],    ah0, false);
            ah1 = __builtin_amdgcn_fdot2(wh_[32+i], rh2p[kb+32+i], ah1, false);
        }
        if (k) s_redB[n] = ah0+ah1;
        __syncthreads();
        if (!k) {
            float preh = ah0+ah1 + s_redB[n] + ph + bh_;
            float tc = fminf(30.f, fmaxf(-30.f, preh));
            float e  = __expf(-2.f*tc);
            float ht = (1.f-e)/(1.f+e);
            h = h + z*(ht - h);                     // (1-z)h + z*ht
            s_h[n] = (_Float16)h;
            if (LAYER == 0) h0chunk[((size_t)b*CH + tl)*HID + n] = __float2half(h);
            pr = prN; pz = pzN; ph = phN;
        }
        __syncthreads();
    }
    if (!k) hstate[((size_t)LAYER*NB + b)*HID + n] = h;

    if (LAYER == 1 && c == NCH-1) {
        if (!k) s_redA[n] = h;
        __syncthreads();
        if (tid < 64) {
            float p0 = 0.f, p1 = 0.f;
#pragma unroll
            for (int m = 0; m < 4; ++m) {
                float hv = s_redA[tid + 64*m];
                p0 += hv * Wfc[(tid+64*m)*2+0];
                p1 += hv * Wfc[(tid+64*m)*2+1];
            }
#pragma unroll
            for (int d = 1; d < 64; d <<= 1) { p0 += __shfl_xor(p0, d); p1 += __shfl_xor(p1, d); }
            if (tid == 0) { out[b*2+0] = p0 + bfc[0]; out[b*2+1] = p1 + bfc[1]; }
        }
    }
}

// ---------------- host ----------------
extern "C" void kernel_launch(void* const* d_in, const int* in_sizes, int n_in,
                              void* d_out, int out_size, void* d_ws, size_t ws_size,
                              hipStream_t stream) {
    const int*   tokens = (const int*)  d_in[0];
    const float* emb    = (const float*)d_in[1];
    const float* Wr     = (const float*)d_in[2];
    const float* br     = (const float*)d_in[3];
    const float* Wz     = (const float*)d_in[4];
    const float* bz     = (const float*)d_in[5];
    const float* Wh     = (const float*)d_in[6];
    const float* bh     = (const float*)d_in[7];
    const float* Wfc    = (const float*)d_in[8];
    const float* bfc    = (const float*)d_in[9];
    float* out = (float*)d_out;

    char* ws = (char*)d_ws;
    uint32_t* wpack  = (uint32_t*)(ws + 0);               //   786,432 B
    __half*   wxt    = (__half*)(ws + (1u<<20));          //   786,432 B
    __half*   embf16 = (__half*)(ws + (2u<<20));          // 16,384,000 B
    __half*   proj0  = (__half*)(ws + 18874368u);         // 25,165,824 B
    __half*   proj1  = (__half*)(ws + 44040192u);         // 25,165,824 B
    __half*   h0chunk= (__half*)(ws + 69206016u);         //  8,388,608 B
    float*    hstate = (float*)(ws + 77594624u);          //    131,072 B  (total ~77.7 MB)

    prep_kernel<<<2048, 256, 0, stream>>>(Wr, Wz, Wh, emb, wpack, wxt, embf16);

    dim3 ggrid(128, 12);   // 16384/128 x 768/64
    for (int c = 0; c < NCH; ++c) {
        gemm_proj<0><<<ggrid, 256, 0, stream>>>(tokens, embf16, h0chunk, wxt, proj0, c);
        rec_kernel<0><<<NB, 512, 0, stream>>>(wpack, proj0, h0chunk, hstate, br,bz,bh, Wfc,bfc, out, c);
        gemm_proj<1><<<ggrid, 256, 0, stream>>>(tokens, embf16, h0chunk, wxt, proj1, c);
        rec_kernel<1><<<NB, 512, 0, stream>>>(wpack, proj1, h0chunk, hstate, br,bz,bh, Wfc,bfc, out, c);
    }
}

// Round 3
// 8614.255 us; speedup vs baseline: 75.4190x; 1.4275x over previous
//
#include <hip/hip_runtime.h>
#include <hip/hip_bf16.h>
#include <hip/hip_fp16.h>
#include <stdint.h>

typedef _Float16 h2_t  __attribute__((ext_vector_type(2)));
typedef _Float16 f16x8 __attribute__((ext_vector_type(8)));
typedef float    f32x4 __attribute__((ext_vector_type(4)));

#define TSEQ 4096
#define HID  256
#define IN2  512
#define NB   64
#define CH   256
#define NCH  16

__device__ __forceinline__ h2_t bc_h2(uint32_t v){ return __builtin_bit_cast(h2_t, v); }

// ---------------- prep: pack recurrent weights, transpose x-weights, emb->f16, bias ----------
__global__ void prep_kernel(const float* __restrict__ Wr, const float* __restrict__ Wz,
                            const float* __restrict__ Wh, const float* __restrict__ emb,
                            const float* __restrict__ br, const float* __restrict__ bz,
                            const float* __restrict__ bh,
                            uint32_t* __restrict__ wpack, __half* __restrict__ wxt,
                            __half* __restrict__ embf16, float* __restrict__ biasv)
{
    const long long S0 = 2LL*3*128*256;      // packed recurrent h-part weights (h2)
    const long long S1 = 2LL*768*256;        // WxT[L][o][k]
    const long long S2 = 32000LL*256;        // emb f16
    const long long S3 = 2LL*768;            // biasv[L][o]
    for (long long idx = (long long)blockIdx.x*256 + threadIdx.x; idx < S0+S1+S2+S3;
         idx += (long long)gridDim.x*256) {
        if (idx < S0) {
            int n   = (int)(idx & 255);
            int kk2 = (int)((idx >> 8) & 127);
            int t   = (int)(idx >> 15);          // 0..5 = L*3+g
            int g = t % 3, L = t / 3;
            const float* Wsrc = (g==0?Wr:(g==1?Wz:Wh)) + (size_t)L*IN2*HID;
            h2_t p;
            p[0] = (_Float16)Wsrc[(256 + 2*kk2)*HID + n];
            p[1] = (_Float16)Wsrc[(257 + 2*kk2)*HID + n];
            wpack[idx] = __builtin_bit_cast(uint32_t, p);
        } else if (idx < S0+S1) {
            int i  = (int)(idx - S0);
            int k  = i & 255;
            int i2 = i >> 8;                     // 0..1535
            int o  = i2 % 768, L = i2 / 768;
            int g  = o >> 8,   n = o & 255;
            const float* Wsrc = (g==0?Wr:(g==1?Wz:Wh)) + (size_t)L*IN2*HID;
            wxt[i] = __float2half(Wsrc[k*HID + n]);   // WxT[L][o][k]
        } else if (idx < S0+S1+S2) {
            int i = (int)(idx - S0 - S1);
            embf16[i] = __float2half(emb[i]);
        } else {
            int i = (int)(idx - S0 - S1 - S2);   // [0, 1536)
            int o = i % 768, L = i / 768;
            int g = o >> 8,  n = o & 255;
            const float* bsrc = (g==0?br:(g==1?bz:bh));
            biasv[i] = bsrc[L*HID + n];
        }
    }
}

// ---------------- x-projection GEMM (both layers in one launch via blockIdx.z) --------------
// proj[r][o] = A[r][:256] @ WxT[Lz] + bias[Lz][o].  z=0: A=embf16[tokens] chunk c0
//                                                   z=1: A=h0chunk (chunk c1 data)
__global__ __launch_bounds__(256) void gemm_proj(
    const int* __restrict__ tokens, const __half* __restrict__ embf16,
    const __half* __restrict__ h0chunk, const __half* __restrict__ wxt,
    const float* __restrict__ biasv,
    __half* __restrict__ proj0, __half* __restrict__ proj1, int c0, int c1)
{
    const int Lz = blockIdx.z;
    const int c  = Lz ? c1 : c0;
    if (c < 0 || c >= NCH) return;
    __half* proj = Lz ? proj1 : proj0;

    __shared__ uint4 Ald[128*17];
    __shared__ uint4 Bld[64*17];
    const int tid = threadIdx.x;
    const int mt = blockIdx.x, nt = blockIdx.y;
    const int w = tid >> 6, l = tid & 63, lr = l & 15, lk = l >> 4;
    f32x4 acc[2][4] = {};

#pragma unroll 1
    for (int kh = 0; kh < 2; ++kh) {
        if (kh) __syncthreads();
#pragma unroll
        for (int it = 0; it < 8; ++it) {
            int idx = it*256 + tid;
            int row = idx >> 4, u4 = idx & 15;
            int grow = mt*128 + row;
            const __half* src;
            if (Lz == 0) {
                int b = grow >> 8, tl = grow & (CH-1);
                int tok = tokens[(size_t)b*TSEQ + c*CH + tl];
                src = embf16 + (size_t)tok*HID;
            } else {
                src = h0chunk + (size_t)grow*HID;
            }
            Ald[row*17 + u4] = ((const uint4*)(src + kh*128))[u4];
        }
#pragma unroll
        for (int it = 0; it < 4; ++it) {
            int idx = it*256 + tid;
            int col = idx >> 4, u4 = idx & 15;
            const __half* src = wxt + ((size_t)(Lz*768 + nt*64 + col))*HID + kh*128;
            Bld[col*17 + u4] = ((const uint4*)src)[u4];
        }
        __syncthreads();
        const _Float16* A = (const _Float16*)Ald;
        const _Float16* B = (const _Float16*)Bld;
#pragma unroll
        for (int kb = 0; kb < 4; ++kb) {
            int k0 = kb*32;
            f16x8 af[2], bf[4];
#pragma unroll
            for (int fm = 0; fm < 2; ++fm) {
                int row = w*32 + fm*16 + lr;
                af[fm] = *(const f16x8*)(A + row*136 + k0 + lk*8);
            }
#pragma unroll
            for (int fn = 0; fn < 4; ++fn) {
                int col = fn*16 + lr;
                bf[fn] = *(const f16x8*)(B + col*136 + k0 + lk*8);
            }
#pragma unroll
            for (int fm = 0; fm < 2; ++fm)
#pragma unroll
                for (int fn = 0; fn < 4; ++fn)
                    acc[fm][fn] = __builtin_amdgcn_mfma_f32_16x16x32_f16(af[fm], bf[fn], acc[fm][fn], 0,0,0);
        }
    }
#pragma unroll
    for (int fm = 0; fm < 2; ++fm)
#pragma unroll
        for (int fn = 0; fn < 4; ++fn)
#pragma unroll
            for (int q = 0; q < 4; ++q) {
                int row = mt*128 + w*32 + fm*16 + lk*4 + q;
                int col = nt*64 + fn*16 + lr;
                float v = acc[fm][fn][q] + biasv[Lz*768 + col];
                proj[(size_t)row*768 + col] = __float2half(v);
            }
}

// ---------------- fused recurrence: blocks 0-63 = L0 chunk c0, 64-127 = L1 chunk c1 ---------
// thread (k4 = tid&3, nb = tid>>2): neurons {nb, nb+128}, K-quarter k4. 192 fdot2/thread/step.
// Cross-k reduce: quad shfl_xor(1),(2). 2 barriers/step.
__global__ __launch_bounds__(512, 2) void rec_fused(
    const uint32_t* __restrict__ wpack,
    const __half* __restrict__ proj0, const __half* __restrict__ proj1,
    __half* __restrict__ h0chunk, float* __restrict__ hstate,
    const float* __restrict__ Wfc, const float* __restrict__ bfc,
    float* __restrict__ out, int c0, int c1)
{
    __shared__ __align__(16) _Float16 s_h[256];
    __shared__ __align__(16) _Float16 s_rh[256];
    __shared__ float s_head[256];

    const int L = blockIdx.x >> 6;
    const int b = blockIdx.x & 63;
    const int c = L ? c1 : c0;
    if (c < 0 || c >= NCH) return;

    const int tid = threadIdx.x;
    const int k4  = tid & 3;
    const int nb  = tid >> 2;            // [0,128)
    const bool wlead = (k4 == 0);

    h2_t wr_[2][32], wz_[2][32], wh_[2][32];
    {
        const uint32_t* wb = wpack + (size_t)(L*3*128)*256;
#pragma unroll
        for (int i = 0; i < 32; ++i) {
            int kk = k4*32 + i;
            wr_[0][i] = bc_h2(wb[(      kk)*256 + nb      ]);
            wr_[1][i] = bc_h2(wb[(      kk)*256 + nb + 128]);
            wz_[0][i] = bc_h2(wb[(128 + kk)*256 + nb      ]);
            wz_[1][i] = bc_h2(wb[(128 + kk)*256 + nb + 128]);
            wh_[0][i] = bc_h2(wb[(256 + kk)*256 + nb      ]);
            wh_[1][i] = bc_h2(wb[(256 + kk)*256 + nb + 128]);
        }
    }

    float h0f, h1f;
    if (c == 0) { h0f = 0.f; h1f = 0.f; }
    else {
        h0f = hstate[(size_t)(L*NB + b)*HID + nb];
        h1f = hstate[(size_t)(L*NB + b)*HID + nb + 128];
    }
    if (wlead) { s_h[nb] = (_Float16)h0f; s_h[nb+128] = (_Float16)h1f; }
    __syncthreads();

    const __half* prow = (L ? proj1 : proj0) + (size_t)b*CH*768;
    const h2_t* h2p  = (const h2_t*)s_h;
    const h2_t* rh2p = (const h2_t*)s_rh;

#pragma unroll 1
    for (int tl = 0; tl < CH; ++tl) {
        const __half* pp = prow + (size_t)tl*768;
        float pr0 = __half2float(pp[nb]);
        float pr1 = __half2float(pp[nb+128]);
        float pz0 = __half2float(pp[256+nb]);
        float pz1 = __half2float(pp[256+nb+128]);
        float ph0 = __half2float(pp[512+nb]);
        float ph1 = __half2float(pp[512+nb+128]);

        // phase A: r,z over h (K-quarter per thread, 4 independent chains)
        float ar0=0.f, ar1=0.f, az0=0.f, az1=0.f;
#pragma unroll
        for (int i = 0; i < 32; ++i) {
            h2_t hv = h2p[k4*32 + i];
            ar0 = __builtin_amdgcn_fdot2(wr_[0][i], hv, ar0, false);
            ar1 = __builtin_amdgcn_fdot2(wr_[1][i], hv, ar1, false);
            az0 = __builtin_amdgcn_fdot2(wz_[0][i], hv, az0, false);
            az1 = __builtin_amdgcn_fdot2(wz_[1][i], hv, az1, false);
        }
        ar0 += __shfl_xor(ar0,1); ar0 += __shfl_xor(ar0,2);
        ar1 += __shfl_xor(ar1,1); ar1 += __shfl_xor(ar1,2);
        az0 += __shfl_xor(az0,1); az0 += __shfl_xor(az0,2);
        az1 += __shfl_xor(az1,1); az1 += __shfl_xor(az1,2);

        float r0 = 1.f/(1.f+__expf(-(ar0+pr0)));
        float r1 = 1.f/(1.f+__expf(-(ar1+pr1)));
        float z0 = 1.f/(1.f+__expf(-(az0+pz0)));
        float z1 = 1.f/(1.f+__expf(-(az1+pz1)));
        if (wlead) { s_rh[nb] = (_Float16)(r0*h0f); s_rh[nb+128] = (_Float16)(r1*h1f); }
        __syncthreads();

        // phase B: candidate over r*h (4 chains for ILP)
        float ah0a=0.f, ah0b=0.f, ah1a=0.f, ah1b=0.f;
#pragma unroll
        for (int i = 0; i < 16; ++i) {
            h2_t ra = rh2p[k4*32 + i];
            h2_t rb = rh2p[k4*32 + 16 + i];
            ah0a = __builtin_amdgcn_fdot2(wh_[0][i],    ra, ah0a, false);
            ah0b = __builtin_amdgcn_fdot2(wh_[0][16+i], rb, ah0b, false);
            ah1a = __builtin_amdgcn_fdot2(wh_[1][i],    ra, ah1a, false);
            ah1b = __builtin_amdgcn_fdot2(wh_[1][16+i], rb, ah1b, false);
        }
        float ah0 = ah0a + ah0b, ah1 = ah1a + ah1b;
        ah0 += __shfl_xor(ah0,1); ah0 += __shfl_xor(ah0,2);
        ah1 += __shfl_xor(ah1,1); ah1 += __shfl_xor(ah1,2);

        float tc0 = fminf(30.f, fmaxf(-30.f, ah0 + ph0));
        float tc1 = fminf(30.f, fmaxf(-30.f, ah1 + ph1));
        float e0 = __expf(-2.f*tc0), e1 = __expf(-2.f*tc1);
        float t0 = (1.f-e0)/(1.f+e0), t1 = (1.f-e1)/(1.f+e1);
        h0f += z0*(t0 - h0f);
        h1f += z1*(t1 - h1f);
        if (wlead) {
            s_h[nb]     = (_Float16)h0f;
            s_h[nb+128] = (_Float16)h1f;
            if (L == 0) {
                __half* hc = h0chunk + ((size_t)b*CH + tl)*HID;
                hc[nb]     = __float2half(h0f);
                hc[nb+128] = __float2half(h1f);
            }
        }
        __syncthreads();
    }

    if (wlead) {
        hstate[(size_t)(L*NB + b)*HID + nb]       = h0f;
        hstate[(size_t)(L*NB + b)*HID + nb + 128] = h1f;
    }

    if (L == 1 && c == NCH-1) {
        if (wlead) { s_head[nb] = h0f; s_head[nb+128] = h1f; }
        __syncthreads();
        if (tid < 64) {
            float p0 = 0.f, p1 = 0.f;
#pragma unroll
            for (int m = 0; m < 4; ++m) {
                float hv = s_head[tid + 64*m];
                p0 += hv * Wfc[(tid+64*m)*2+0];
                p1 += hv * Wfc[(tid+64*m)*2+1];
            }
#pragma unroll
            for (int d = 1; d < 64; d <<= 1) { p0 += __shfl_xor(p0, d); p1 += __shfl_xor(p1, d); }
            if (tid == 0) { out[b*2+0] = p0 + bfc[0]; out[b*2+1] = p1 + bfc[1]; }
        }
    }
}

// ---------------- host ----------------
extern "C" void kernel_launch(void* const* d_in, const int* in_sizes, int n_in,
                              void* d_out, int out_size, void* d_ws, size_t ws_size,
                              hipStream_t stream) {
    const int*   tokens = (const int*)  d_in[0];
    const float* emb    = (const float*)d_in[1];
    const float* Wr     = (const float*)d_in[2];
    const float* br     = (const float*)d_in[3];
    const float* Wz     = (const float*)d_in[4];
    const float* bz     = (const float*)d_in[5];
    const float* Wh     = (const float*)d_in[6];
    const float* bh     = (const float*)d_in[7];
    const float* Wfc    = (const float*)d_in[8];
    const float* bfc    = (const float*)d_in[9];
    float* out = (float*)d_out;

    char* ws = (char*)d_ws;
    uint32_t* wpack  = (uint32_t*)(ws + 0);               //   786,432 B
    __half*   wxt    = (__half*)(ws + (1u<<20));          //   786,432 B
    __half*   embf16 = (__half*)(ws + (2u<<20));          // 16,384,000 B
    __half*   proj0  = (__half*)(ws + 18874368u);         // 25,165,824 B
    __half*   proj1  = (__half*)(ws + 44040192u);         // 25,165,824 B
    __half*   h0chunk= (__half*)(ws + 69206016u);         //  8,388,608 B
    float*    hstate = (float*)(ws + 77594624u);          //    131,072 B
    float*    biasv  = (float*)(ws + 77725696u);          //      6,144 B

    prep_kernel<<<2048, 256, 0, stream>>>(Wr, Wz, Wh, emb, br, bz, bh, wpack, wxt, embf16, biasv);

    dim3 ggrid(128, 12, 2);
    for (int c = 0; c <= NCH; ++c) {
        int cc0 = (c < NCH) ? c : -1;
        int cc1 = c - 1;
        gemm_proj<<<ggrid, 256, 0, stream>>>(tokens, embf16, h0chunk, wxt, biasv, proj0, proj1, cc0, cc1);
        rec_fused<<<128, 512, 0, stream>>>(wpack, proj0, proj1, h0chunk, hstate, Wfc, bfc, out, cc0, cc1);
    }
}

// Round 4
// 7819.808 us; speedup vs baseline: 83.0811x; 1.1016x over previous
//
#include <hip/hip_runtime.h>
#include <hip/hip_bf16.h>
#include <hip/hip_fp16.h>
#include <stdint.h>

typedef _Float16 h2_t  __attribute__((ext_vector_type(2)));
typedef _Float16 f16x8 __attribute__((ext_vector_type(8)));
typedef float    f32x4 __attribute__((ext_vector_type(4)));

#define TSEQ 4096
#define HID  256
#define IN2  512
#define NB   64
#define CH   256
#define NCH  16

__device__ __forceinline__ h2_t bc_h2(uint32_t v){ return __builtin_bit_cast(h2_t, v); }

// quad butterfly reduce via DPP (VALU pipe, not LDS)
__device__ __forceinline__ float quad_reduce(float x){
    float t;
    t = __builtin_bit_cast(float, __builtin_amdgcn_mov_dpp(__builtin_bit_cast(int, x), 0xB1, 0xF, 0xF, true));
    x += t;
    t = __builtin_bit_cast(float, __builtin_amdgcn_mov_dpp(__builtin_bit_cast(int, x), 0x4E, 0xF, 0xF, true));
    x += t;
    return x;
}

// ---------------- prep: pack recurrent weights, transpose x-weights, emb->f16, bias ----------
__global__ void prep_kernel(const float* __restrict__ Wr, const float* __restrict__ Wz,
                            const float* __restrict__ Wh, const float* __restrict__ emb,
                            const float* __restrict__ br, const float* __restrict__ bz,
                            const float* __restrict__ bh,
                            uint32_t* __restrict__ wpack, __half* __restrict__ wxt,
                            __half* __restrict__ embf16, float* __restrict__ biasv)
{
    const long long S0 = 2LL*3*128*256;      // packed recurrent h-part weights (h2)
    const long long S1 = 2LL*768*256;        // WxT[L][o][k]
    const long long S2 = 32000LL*256;        // emb f16
    const long long S3 = 2LL*768;            // biasv[L][o]
    for (long long idx = (long long)blockIdx.x*256 + threadIdx.x; idx < S0+S1+S2+S3;
         idx += (long long)gridDim.x*256) {
        if (idx < S0) {
            int n   = (int)(idx & 255);
            int kk2 = (int)((idx >> 8) & 127);
            int t   = (int)(idx >> 15);          // 0..5 = L*3+g
            int g = t % 3, L = t / 3;
            const float* Wsrc = (g==0?Wr:(g==1?Wz:Wh)) + (size_t)L*IN2*HID;
            h2_t p;
            p[0] = (_Float16)Wsrc[(256 + 2*kk2)*HID + n];
            p[1] = (_Float16)Wsrc[(257 + 2*kk2)*HID + n];
            wpack[idx] = __builtin_bit_cast(uint32_t, p);
        } else if (idx < S0+S1) {
            int i  = (int)(idx - S0);
            int k  = i & 255;
            int i2 = i >> 8;                     // 0..1535
            int o  = i2 % 768, L = i2 / 768;
            int g  = o >> 8,   n = o & 255;
            const float* Wsrc = (g==0?Wr:(g==1?Wz:Wh)) + (size_t)L*IN2*HID;
            wxt[i] = __float2half(Wsrc[k*HID + n]);   // WxT[L][o][k]
        } else if (idx < S0+S1+S2) {
            int i = (int)(idx - S0 - S1);
            embf16[i] = __float2half(emb[i]);
        } else {
            int i = (int)(idx - S0 - S1 - S2);   // [0, 1536)
            int o = i % 768, L = i / 768;
            int g = o >> 8,  n = o & 255;
            const float* bsrc = (g==0?br:(g==1?bz:bh));
            biasv[i] = bsrc[L*HID + n];
        }
    }
}

// ---------------- x-projection GEMM (both layers in one launch via blockIdx.z) --------------
__global__ __launch_bounds__(256) void gemm_proj(
    const int* __restrict__ tokens, const __half* __restrict__ embf16,
    const __half* __restrict__ h0chunk, const __half* __restrict__ wxt,
    const float* __restrict__ biasv,
    __half* __restrict__ proj0, __half* __restrict__ proj1, int c0, int c1)
{
    const int Lz = blockIdx.z;
    const int c  = Lz ? c1 : c0;
    if (c < 0 || c >= NCH) return;
    __half* proj = Lz ? proj1 : proj0;

    __shared__ uint4 Ald[128*17];
    __shared__ uint4 Bld[64*17];
    const int tid = threadIdx.x;
    const int mt = blockIdx.x, nt = blockIdx.y;
    const int w = tid >> 6, l = tid & 63, lr = l & 15, lk = l >> 4;
    f32x4 acc[2][4] = {};

#pragma unroll 1
    for (int kh = 0; kh < 2; ++kh) {
        if (kh) __syncthreads();
#pragma unroll
        for (int it = 0; it < 8; ++it) {
            int idx = it*256 + tid;
            int row = idx >> 4, u4 = idx & 15;
            int grow = mt*128 + row;
            const __half* src;
            if (Lz == 0) {
                int b = grow >> 8, tl = grow & (CH-1);
                int tok = tokens[(size_t)b*TSEQ + c*CH + tl];
                src = embf16 + (size_t)tok*HID;
            } else {
                src = h0chunk + (size_t)grow*HID;
            }
            Ald[row*17 + u4] = ((const uint4*)(src + kh*128))[u4];
        }
#pragma unroll
        for (int it = 0; it < 4; ++it) {
            int idx = it*256 + tid;
            int col = idx >> 4, u4 = idx & 15;
            const __half* src = wxt + ((size_t)(Lz*768 + nt*64 + col))*HID + kh*128;
            Bld[col*17 + u4] = ((const uint4*)src)[u4];
        }
        __syncthreads();
        const _Float16* A = (const _Float16*)Ald;
        const _Float16* B = (const _Float16*)Bld;
#pragma unroll
        for (int kb = 0; kb < 4; ++kb) {
            int k0 = kb*32;
            f16x8 af[2], bf[4];
#pragma unroll
            for (int fm = 0; fm < 2; ++fm) {
                int row = w*32 + fm*16 + lr;
                af[fm] = *(const f16x8*)(A + row*136 + k0 + lk*8);
            }
#pragma unroll
            for (int fn = 0; fn < 4; ++fn) {
                int col = fn*16 + lr;
                bf[fn] = *(const f16x8*)(B + col*136 + k0 + lk*8);
            }
#pragma unroll
            for (int fm = 0; fm < 2; ++fm)
#pragma unroll
                for (int fn = 0; fn < 4; ++fn)
                    acc[fm][fn] = __builtin_amdgcn_mfma_f32_16x16x32_f16(af[fm], bf[fn], acc[fm][fn], 0,0,0);
        }
    }
#pragma unroll
    for (int fm = 0; fm < 2; ++fm)
#pragma unroll
        for (int fn = 0; fn < 4; ++fn)
#pragma unroll
            for (int q = 0; q < 4; ++q) {
                int row = mt*128 + w*32 + fm*16 + lk*4 + q;
                int col = nt*64 + fn*16 + lr;
                float v = acc[fm][fn][q] + biasv[Lz*768 + col];
                proj[(size_t)row*768 + col] = __float2half(v);
            }
}

// ---------------- fused recurrence: blocks 0-63 = L0 chunk c0, 64-127 = L1 chunk c1 ---------
// thread (k4 = tid&3, nb = tid>>2): neurons {nb, nb+128}, K-quarter k4.
// LDS reads rotated per-k4 (bank-conflict-free); weights asm-pinned in VGPRs.
__global__ __launch_bounds__(512, 2) void rec_fused(
    const uint32_t* __restrict__ wpack,
    const __half* __restrict__ proj0, const __half* __restrict__ proj1,
    __half* __restrict__ h0chunk, float* __restrict__ hstate,
    const float* __restrict__ Wfc, const float* __restrict__ bfc,
    float* __restrict__ out, int c0, int c1)
{
    __shared__ __align__(16) _Float16 s_h[256];
    __shared__ __align__(16) _Float16 s_rh[256];
    __shared__ float s_head[256];

    const int L = blockIdx.x >> 6;
    const int b = blockIdx.x & 63;
    const int c = L ? c1 : c0;
    if (c < 0 || c >= NCH) return;

    const int tid = threadIdx.x;
    const int k4  = tid & 3;
    const int nb  = tid >> 2;            // [0,128)
    const bool wlead = (k4 == 0);

    // weights as raw u32, load order permuted to match rotated LDS reads:
    // reg index i = u*4+j  <->  K-h2 index  k4*32 + ((u+k4)&7)*4 + j
    uint32_t wr_[2][32], wz_[2][32], wh_[2][32];
    {
        const uint32_t* wb = wpack + (size_t)(L*3*128)*256;
#pragma unroll
        for (int u = 0; u < 8; ++u)
#pragma unroll
            for (int j = 0; j < 4; ++j) {
                int i  = u*4 + j;
                int kk = k4*32 + (((u + k4) & 7)*4 + j);
                wr_[0][i] = wb[(      kk)*256 + nb      ];
                wr_[1][i] = wb[(      kk)*256 + nb + 128];
                wz_[0][i] = wb[(128 + kk)*256 + nb      ];
                wz_[1][i] = wb[(128 + kk)*256 + nb + 128];
                wh_[0][i] = wb[(256 + kk)*256 + nb      ];
                wh_[1][i] = wb[(256 + kk)*256 + nb + 128];
            }
    }
    // pin: make values asm-opaque so the compiler cannot re-load them per iteration
#pragma unroll
    for (int i = 0; i < 32; ++i) {
        asm volatile("" : "+v"(wr_[0][i]), "+v"(wr_[1][i]), "+v"(wz_[0][i]),
                          "+v"(wz_[1][i]), "+v"(wh_[0][i]), "+v"(wh_[1][i]));
    }

    float h0f, h1f;
    if (c == 0) { h0f = 0.f; h1f = 0.f; }
    else {
        h0f = hstate[(size_t)(L*NB + b)*HID + nb];
        h1f = hstate[(size_t)(L*NB + b)*HID + nb + 128];
    }
    if (wlead) { s_h[nb] = (_Float16)h0f; s_h[nb+128] = (_Float16)h1f; }
    __syncthreads();

    const __half* prow = (L ? proj1 : proj0) + (size_t)b*CH*768;
    const h2_t* h2p  = (const h2_t*)s_h;
    const h2_t* rh2p = (const h2_t*)s_rh;

#pragma unroll 1
    for (int tl = 0; tl < CH; ++tl) {
        const __half* pp = prow + (size_t)tl*768;
        float pr0 = __half2float(pp[nb]);
        float pr1 = __half2float(pp[nb+128]);
        float pz0 = __half2float(pp[256+nb]);
        float pz1 = __half2float(pp[256+nb+128]);
        float ph0 = __half2float(pp[512+nb]);
        float ph1 = __half2float(pp[512+nb+128]);

        // phase A: r,z over h; rotated reads (conflict-free across k4)
        float ar0=0.f, ar1=0.f, az0=0.f, az1=0.f;
        {
            const h2_t* hq = h2p + k4*32;
#pragma unroll
            for (int u = 0; u < 8; ++u) {
                int ru = ((u + k4) & 7)*4;
#pragma unroll
                for (int j = 0; j < 4; ++j) {
                    h2_t hv = hq[ru + j];
                    int i = u*4 + j;
                    ar0 = __builtin_amdgcn_fdot2(bc_h2(wr_[0][i]), hv, ar0, false);
                    ar1 = __builtin_amdgcn_fdot2(bc_h2(wr_[1][i]), hv, ar1, false);
                    az0 = __builtin_amdgcn_fdot2(bc_h2(wz_[0][i]), hv, az0, false);
                    az1 = __builtin_amdgcn_fdot2(bc_h2(wz_[1][i]), hv, az1, false);
                }
            }
        }
        ar0 = quad_reduce(ar0); ar1 = quad_reduce(ar1);
        az0 = quad_reduce(az0); az1 = quad_reduce(az1);

        float r0 = 1.f/(1.f+__expf(-(ar0+pr0)));
        float r1 = 1.f/(1.f+__expf(-(ar1+pr1)));
        float z0 = 1.f/(1.f+__expf(-(az0+pz0)));
        float z1 = 1.f/(1.f+__expf(-(az1+pz1)));
        if (wlead) { s_rh[nb] = (_Float16)(r0*h0f); s_rh[nb+128] = (_Float16)(r1*h1f); }
        __syncthreads();

        // phase B: candidate over r*h; same rotation, 2 chains per neuron
        float ah0a=0.f, ah0b=0.f, ah1a=0.f, ah1b=0.f;
        {
            const h2_t* rq = rh2p + k4*32;
#pragma unroll
            for (int u = 0; u < 8; ++u) {
                int ru = ((u + k4) & 7)*4;
#pragma unroll
                for (int j = 0; j < 4; ++j) {
                    h2_t rv = rq[ru + j];
                    int i = u*4 + j;
                    if (j & 1) {
                        ah0b = __builtin_amdgcn_fdot2(bc_h2(wh_[0][i]), rv, ah0b, false);
                        ah1b = __builtin_amdgcn_fdot2(bc_h2(wh_[1][i]), rv, ah1b, false);
                    } else {
                        ah0a = __builtin_amdgcn_fdot2(bc_h2(wh_[0][i]), rv, ah0a, false);
                        ah1a = __builtin_amdgcn_fdot2(bc_h2(wh_[1][i]), rv, ah1a, false);
                    }
                }
            }
        }
        float ah0 = quad_reduce(ah0a + ah0b);
        float ah1 = quad_reduce(ah1a + ah1b);

        float tc0 = fminf(30.f, fmaxf(-30.f, ah0 + ph0));
        float tc1 = fminf(30.f, fmaxf(-30.f, ah1 + ph1));
        float e0 = __expf(-2.f*tc0), e1 = __expf(-2.f*tc1);
        float t0 = (1.f-e0)/(1.f+e0), t1 = (1.f-e1)/(1.f+e1);
        h0f += z0*(t0 - h0f);
        h1f += z1*(t1 - h1f);
        if (wlead) {
            s_h[nb]     = (_Float16)h0f;
            s_h[nb+128] = (_Float16)h1f;
            if (L == 0) {
                __half* hc = h0chunk + ((size_t)b*CH + tl)*HID;
                hc[nb]     = __float2half(h0f);
                hc[nb+128] = __float2half(h1f);
            }
        }
        __syncthreads();
    }

    if (wlead) {
        hstate[(size_t)(L*NB + b)*HID + nb]       = h0f;
        hstate[(size_t)(L*NB + b)*HID + nb + 128] = h1f;
    }

    if (L == 1 && c == NCH-1) {
        if (wlead) { s_head[nb] = h0f; s_head[nb+128] = h1f; }
        __syncthreads();
        if (tid < 64) {
            float p0 = 0.f, p1 = 0.f;
#pragma unroll
            for (int m = 0; m < 4; ++m) {
                float hv = s_head[tid + 64*m];
                p0 += hv * Wfc[(tid+64*m)*2+0];
                p1 += hv * Wfc[(tid+64*m)*2+1];
            }
#pragma unroll
            for (int d = 1; d < 64; d <<= 1) { p0 += __shfl_xor(p0, d); p1 += __shfl_xor(p1, d); }
            if (tid == 0) { out[b*2+0] = p0 + bfc[0]; out[b*2+1] = p1 + bfc[1]; }
        }
    }
}

// ---------------- host ----------------
extern "C" void kernel_launch(void* const* d_in, const int* in_sizes, int n_in,
                              void* d_out, int out_size, void* d_ws, size_t ws_size,
                              hipStream_t stream) {
    const int*   tokens = (const int*)  d_in[0];
    const float* emb    = (const float*)d_in[1];
    const float* Wr     = (const float*)d_in[2];
    const float* br     = (const float*)d_in[3];
    const float* Wz     = (const float*)d_in[4];
    const float* bz     = (const float*)d_in[5];
    const float* Wh     = (const float*)d_in[6];
    const float* bh     = (const float*)d_in[7];
    const float* Wfc    = (const float*)d_in[8];
    const float* bfc    = (const float*)d_in[9];
    float* out = (float*)d_out;

    char* ws = (char*)d_ws;
    uint32_t* wpack  = (uint32_t*)(ws + 0);               //   786,432 B
    __half*   wxt    = (__half*)(ws + (1u<<20));          //   786,432 B
    __half*   embf16 = (__half*)(ws + (2u<<20));          // 16,384,000 B
    __half*   proj0  = (__half*)(ws + 18874368u);         // 25,165,824 B
    __half*   proj1  = (__half*)(ws + 44040192u);         // 25,165,824 B
    __half*   h0chunk= (__half*)(ws + 69206016u);         //  8,388,608 B
    float*    hstate = (float*)(ws + 77594624u);          //    131,072 B
    float*    biasv  = (float*)(ws + 77725696u);          //      6,144 B

    prep_kernel<<<2048, 256, 0, stream>>>(Wr, Wz, Wh, emb, br, bz, bh, wpack, wxt, embf16, biasv);

    dim3 ggrid(128, 12, 2);
    for (int c = 0; c <= NCH; ++c) {
        int cc0 = (c < NCH) ? c : -1;
        int cc1 = c - 1;
        gemm_proj<<<ggrid, 256, 0, stream>>>(tokens, embf16, h0chunk, wxt, biasv, proj0, proj1, cc0, cc1);
        rec_fused<<<128, 512, 0, stream>>>(wpack, proj0, proj1, h0chunk, hstate, Wfc, bfc, out, cc0, cc1);
    }
}

// Round 5
// 7168.666 us; speedup vs baseline: 90.6275x; 1.0908x over previous
//
#include <hip/hip_runtime.h>
#include <hip/hip_bf16.h>
#include <hip/hip_fp16.h>
#include <stdint.h>

typedef _Float16 h2_t  __attribute__((ext_vector_type(2)));
typedef _Float16 f16x8 __attribute__((ext_vector_type(8)));
typedef float    f32x4 __attribute__((ext_vector_type(4)));

#define TSEQ 4096
#define HID  256
#define IN2  512
#define NB   64
#define CH   256
#define NCH  16

__device__ __forceinline__ h2_t bc_h2(uint32_t v){ return __builtin_bit_cast(h2_t, v); }

// quad butterfly reduce via DPP (VALU pipe, not LDS)
__device__ __forceinline__ float quad_reduce(float x){
    float t;
    t = __builtin_bit_cast(float, __builtin_amdgcn_mov_dpp(__builtin_bit_cast(int, x), 0xB1, 0xF, 0xF, true));
    x += t;
    t = __builtin_bit_cast(float, __builtin_amdgcn_mov_dpp(__builtin_bit_cast(int, x), 0x4E, 0xF, 0xF, true));
    x += t;
    return x;
}

// ---------------- prep: pack recurrent weights, transpose x-weights, emb->f16, bias ----------
__global__ void prep_kernel(const float* __restrict__ Wr, const float* __restrict__ Wz,
                            const float* __restrict__ Wh, const float* __restrict__ emb,
                            const float* __restrict__ br, const float* __restrict__ bz,
                            const float* __restrict__ bh,
                            uint32_t* __restrict__ wpack, __half* __restrict__ wxt,
                            __half* __restrict__ embf16, float* __restrict__ biasv)
{
    const long long S0 = 2LL*3*128*256;      // packed recurrent h-part weights (h2)
    const long long S1 = 2LL*768*256;        // WxT[L][o][k]
    const long long S2 = 32000LL*256;        // emb f16
    const long long S3 = 2LL*768;            // biasv[L][o]
    for (long long idx = (long long)blockIdx.x*256 + threadIdx.x; idx < S0+S1+S2+S3;
         idx += (long long)gridDim.x*256) {
        if (idx < S0) {
            int n   = (int)(idx & 255);
            int kk2 = (int)((idx >> 8) & 127);
            int t   = (int)(idx >> 15);          // 0..5 = L*3+g
            int g = t % 3, L = t / 3;
            const float* Wsrc = (g==0?Wr:(g==1?Wz:Wh)) + (size_t)L*IN2*HID;
            h2_t p;
            p[0] = (_Float16)Wsrc[(256 + 2*kk2)*HID + n];
            p[1] = (_Float16)Wsrc[(257 + 2*kk2)*HID + n];
            wpack[idx] = __builtin_bit_cast(uint32_t, p);
        } else if (idx < S0+S1) {
            int i  = (int)(idx - S0);
            int k  = i & 255;
            int i2 = i >> 8;                     // 0..1535
            int o  = i2 % 768, L = i2 / 768;
            int g  = o >> 8,   n = o & 255;
            const float* Wsrc = (g==0?Wr:(g==1?Wz:Wh)) + (size_t)L*IN2*HID;
            wxt[i] = __float2half(Wsrc[k*HID + n]);   // WxT[L][o][k]
        } else if (idx < S0+S1+S2) {
            int i = (int)(idx - S0 - S1);
            embf16[i] = __float2half(emb[i]);
        } else {
            int i = (int)(idx - S0 - S1 - S2);   // [0, 1536)
            int o = i % 768, L = i / 768;
            int g = o >> 8,  n = o & 255;
            const float* bsrc = (g==0?br:(g==1?bz:bh));
            biasv[i] = bsrc[L*HID + n];
        }
    }
}

// ---------------- x-projection GEMM (both layers in one launch via blockIdx.z) --------------
// packed proj layout: off(col) = (col>>8)*256 + (col&127)*2 + ((col>>7)&1)
//   -> u32 word g*128+nb holds (val[nb], val[nb+128]) for gate g
__global__ __launch_bounds__(256) void gemm_proj(
    const int* __restrict__ tokens, const __half* __restrict__ embf16,
    const __half* __restrict__ h0chunk, const __half* __restrict__ wxt,
    const float* __restrict__ biasv,
    __half* __restrict__ proj0, __half* __restrict__ proj1, int c0, int c1)
{
    const int Lz = blockIdx.z;
    const int c  = Lz ? c1 : c0;
    if (c < 0 || c >= NCH) return;
    __half* proj = Lz ? proj1 : proj0;

    __shared__ uint4 Ald[128*17];
    __shared__ uint4 Bld[64*17];
    const int tid = threadIdx.x;
    const int mt = blockIdx.x, nt = blockIdx.y;
    const int w = tid >> 6, l = tid & 63, lr = l & 15, lk = l >> 4;
    f32x4 acc[2][4] = {};

#pragma unroll 1
    for (int kh = 0; kh < 2; ++kh) {
        if (kh) __syncthreads();
#pragma unroll
        for (int it = 0; it < 8; ++it) {
            int idx = it*256 + tid;
            int row = idx >> 4, u4 = idx & 15;
            int grow = mt*128 + row;
            const __half* src;
            if (Lz == 0) {
                int b = grow >> 8, tl = grow & (CH-1);
                int tok = tokens[(size_t)b*TSEQ + c*CH + tl];
                src = embf16 + (size_t)tok*HID;
            } else {
                src = h0chunk + (size_t)grow*HID;
            }
            Ald[row*17 + u4] = ((const uint4*)(src + kh*128))[u4];
        }
#pragma unroll
        for (int it = 0; it < 4; ++it) {
            int idx = it*256 + tid;
            int col = idx >> 4, u4 = idx & 15;
            const __half* src = wxt + ((size_t)(Lz*768 + nt*64 + col))*HID + kh*128;
            Bld[col*17 + u4] = ((const uint4*)src)[u4];
        }
        __syncthreads();
        const _Float16* A = (const _Float16*)Ald;
        const _Float16* B = (const _Float16*)Bld;
#pragma unroll
        for (int kb = 0; kb < 4; ++kb) {
            int k0 = kb*32;
            f16x8 af[2], bf[4];
#pragma unroll
            for (int fm = 0; fm < 2; ++fm) {
                int row = w*32 + fm*16 + lr;
                af[fm] = *(const f16x8*)(A + row*136 + k0 + lk*8);
            }
#pragma unroll
            for (int fn = 0; fn < 4; ++fn) {
                int col = fn*16 + lr;
                bf[fn] = *(const f16x8*)(B + col*136 + k0 + lk*8);
            }
#pragma unroll
            for (int fm = 0; fm < 2; ++fm)
#pragma unroll
                for (int fn = 0; fn < 4; ++fn)
                    acc[fm][fn] = __builtin_amdgcn_mfma_f32_16x16x32_f16(af[fm], bf[fn], acc[fm][fn], 0,0,0);
        }
    }
#pragma unroll
    for (int fm = 0; fm < 2; ++fm)
#pragma unroll
        for (int fn = 0; fn < 4; ++fn)
#pragma unroll
            for (int q = 0; q < 4; ++q) {
                int row = mt*128 + w*32 + fm*16 + lk*4 + q;
                int col = nt*64 + fn*16 + lr;
                float v = acc[fm][fn][q] + biasv[Lz*768 + col];
                int po = ((col >> 8) << 8) + ((col & 127) << 1) + ((col >> 7) & 1);
                proj[(size_t)row*768 + po] = __float2half(v);
            }
}

// ---------------- fused recurrence: blocks 0-63 = L0 chunk c0, 64-127 = L1 chunk c1 ---------
// thread (k4 = tid&3, nb = tid>>2): neurons {nb, nb+128}, K-quarter k4.
// Explicit uint4 LDS reads (b128), per-k4 rotation (conflict-free), proj prefetch t+1.
__global__ __launch_bounds__(512, 2) void rec_fused(
    const uint32_t* __restrict__ wpack,
    const __half* __restrict__ proj0, const __half* __restrict__ proj1,
    __half* __restrict__ h0chunk, float* __restrict__ hstate,
    const float* __restrict__ Wfc, const float* __restrict__ bfc,
    float* __restrict__ out, int c0, int c1)
{
    __shared__ __align__(16) _Float16 s_h[256];
    __shared__ __align__(16) _Float16 s_rh[256];
    __shared__ float s_head[256];

    const int L = blockIdx.x >> 6;
    const int b = blockIdx.x & 63;
    const int c = L ? c1 : c0;
    if (c < 0 || c >= NCH) return;

    const int tid = threadIdx.x;
    const int k4  = tid & 3;
    const int nb  = tid >> 2;            // [0,128)
    const bool wlead = (k4 == 0);

    // weights as raw u32, load order permuted to match rotated LDS reads:
    // reg index i = u*4+j  <->  K-h2 index  k4*32 + ((u+k4)&7)*4 + j
    uint32_t wr_[2][32], wz_[2][32], wh_[2][32];
    {
        const uint32_t* wb = wpack + (size_t)(L*3*128)*256;
#pragma unroll
        for (int u = 0; u < 8; ++u)
#pragma unroll
            for (int j = 0; j < 4; ++j) {
                int i  = u*4 + j;
                int kk = k4*32 + (((u + k4) & 7)*4 + j);
                wr_[0][i] = wb[(      kk)*256 + nb      ];
                wr_[1][i] = wb[(      kk)*256 + nb + 128];
                wz_[0][i] = wb[(128 + kk)*256 + nb      ];
                wz_[1][i] = wb[(128 + kk)*256 + nb + 128];
                wh_[0][i] = wb[(256 + kk)*256 + nb      ];
                wh_[1][i] = wb[(256 + kk)*256 + nb + 128];
            }
    }
    // pin: make values asm-opaque so the compiler cannot re-load them per iteration
#pragma unroll
    for (int i = 0; i < 32; ++i) {
        asm volatile("" : "+v"(wr_[0][i]), "+v"(wr_[1][i]), "+v"(wz_[0][i]),
                          "+v"(wz_[1][i]), "+v"(wh_[0][i]), "+v"(wh_[1][i]));
    }

    float h0f, h1f;
    if (c == 0) { h0f = 0.f; h1f = 0.f; }
    else {
        h0f = hstate[(size_t)(L*NB + b)*HID + nb];
        h1f = hstate[(size_t)(L*NB + b)*HID + nb + 128];
    }
    if (wlead) { s_h[nb] = (_Float16)h0f; s_h[nb+128] = (_Float16)h1f; }
    __syncthreads();

    const uint32_t* prow = (const uint32_t*)((L ? proj1 : proj0) + (size_t)b*CH*768);
    const uint4* hq4  = ((const uint4*)s_h)  + k4*8;   // quarter = 8 uint4 (128B)
    const uint4* rq4  = ((const uint4*)s_rh) + k4*8;

    // proj prefetch registers (packed u32: lo = neuron nb, hi = nb+128)
    uint32_t pj0 = prow[        nb];
    uint32_t pj1 = prow[128 +   nb];
    uint32_t pj2 = prow[256 +   nb];

#pragma unroll 1
    for (int tl = 0; tl < CH; ++tl) {
        // prefetch next step's packed proj words
        int tn = (tl + 1 < CH) ? tl + 1 : tl;
        const uint32_t* pnx = prow + (size_t)tn*384;
        uint32_t pj0N = pnx[        nb];
        uint32_t pj1N = pnx[128 +   nb];
        uint32_t pj2N = pnx[256 +   nb];

        // phase A: r,z over h; explicit b128 reads, rotated (conflict-free across k4)
        uint4 hv[8];
#pragma unroll
        for (int u = 0; u < 8; ++u) hv[u] = hq4[(u + k4) & 7];

        float ar0=0.f, ar1=0.f, az0=0.f, az1=0.f;
#pragma unroll
        for (int u = 0; u < 8; ++u) {
            int i = u*4;
            ar0 = __builtin_amdgcn_fdot2(bc_h2(wr_[0][i  ]), bc_h2(hv[u].x), ar0, false);
            ar1 = __builtin_amdgcn_fdot2(bc_h2(wr_[1][i  ]), bc_h2(hv[u].x), ar1, false);
            az0 = __builtin_amdgcn_fdot2(bc_h2(wz_[0][i  ]), bc_h2(hv[u].x), az0, false);
            az1 = __builtin_amdgcn_fdot2(bc_h2(wz_[1][i  ]), bc_h2(hv[u].x), az1, false);
            ar0 = __builtin_amdgcn_fdot2(bc_h2(wr_[0][i+1]), bc_h2(hv[u].y), ar0, false);
            ar1 = __builtin_amdgcn_fdot2(bc_h2(wr_[1][i+1]), bc_h2(hv[u].y), ar1, false);
            az0 = __builtin_amdgcn_fdot2(bc_h2(wz_[0][i+1]), bc_h2(hv[u].y), az0, false);
            az1 = __builtin_amdgcn_fdot2(bc_h2(wz_[1][i+1]), bc_h2(hv[u].y), az1, false);
            ar0 = __builtin_amdgcn_fdot2(bc_h2(wr_[0][i+2]), bc_h2(hv[u].z), ar0, false);
            ar1 = __builtin_amdgcn_fdot2(bc_h2(wr_[1][i+2]), bc_h2(hv[u].z), ar1, false);
            az0 = __builtin_amdgcn_fdot2(bc_h2(wz_[0][i+2]), bc_h2(hv[u].z), az0, false);
            az1 = __builtin_amdgcn_fdot2(bc_h2(wz_[1][i+2]), bc_h2(hv[u].z), az1, false);
            ar0 = __builtin_amdgcn_fdot2(bc_h2(wr_[0][i+3]), bc_h2(hv[u].w), ar0, false);
            ar1 = __builtin_amdgcn_fdot2(bc_h2(wr_[1][i+3]), bc_h2(hv[u].w), ar1, false);
            az0 = __builtin_amdgcn_fdot2(bc_h2(wz_[0][i+3]), bc_h2(hv[u].w), az0, false);
            az1 = __builtin_amdgcn_fdot2(bc_h2(wz_[1][i+3]), bc_h2(hv[u].w), az1, false);
        }
        ar0 = quad_reduce(ar0); ar1 = quad_reduce(ar1);
        az0 = quad_reduce(az0); az1 = quad_reduce(az1);

        h2_t pjr = bc_h2(pj0), pjz = bc_h2(pj1);
        float r0 = 1.f/(1.f+__expf(-(ar0+(float)pjr[0])));
        float r1 = 1.f/(1.f+__expf(-(ar1+(float)pjr[1])));
        float z0 = 1.f/(1.f+__expf(-(az0+(float)pjz[0])));
        float z1 = 1.f/(1.f+__expf(-(az1+(float)pjz[1])));
        if (wlead) { s_rh[nb] = (_Float16)(r0*h0f); s_rh[nb+128] = (_Float16)(r1*h1f); }
        __syncthreads();

        // phase B: candidate over r*h; same rotation
        uint4 rv[8];
#pragma unroll
        for (int u = 0; u < 8; ++u) rv[u] = rq4[(u + k4) & 7];

        float ah0a=0.f, ah0b=0.f, ah1a=0.f, ah1b=0.f;
#pragma unroll
        for (int u = 0; u < 8; ++u) {
            int i = u*4;
            ah0a = __builtin_amdgcn_fdot2(bc_h2(wh_[0][i  ]), bc_h2(rv[u].x), ah0a, false);
            ah1a = __builtin_amdgcn_fdot2(bc_h2(wh_[1][i  ]), bc_h2(rv[u].x), ah1a, false);
            ah0b = __builtin_amdgcn_fdot2(bc_h2(wh_[0][i+1]), bc_h2(rv[u].y), ah0b, false);
            ah1b = __builtin_amdgcn_fdot2(bc_h2(wh_[1][i+1]), bc_h2(rv[u].y), ah1b, false);
            ah0a = __builtin_amdgcn_fdot2(bc_h2(wh_[0][i+2]), bc_h2(rv[u].z), ah0a, false);
            ah1a = __builtin_amdgcn_fdot2(bc_h2(wh_[1][i+2]), bc_h2(rv[u].z), ah1a, false);
            ah0b = __builtin_amdgcn_fdot2(bc_h2(wh_[0][i+3]), bc_h2(rv[u].w), ah0b, false);
            ah1b = __builtin_amdgcn_fdot2(bc_h2(wh_[1][i+3]), bc_h2(rv[u].w), ah1b, false);
        }
        float ah0 = quad_reduce(ah0a + ah0b);
        float ah1 = quad_reduce(ah1a + ah1b);

        h2_t pjh = bc_h2(pj2);
        float tc0 = fminf(30.f, fmaxf(-30.f, ah0 + (float)pjh[0]));
        float tc1 = fminf(30.f, fmaxf(-30.f, ah1 + (float)pjh[1]));
        float e0 = __expf(-2.f*tc0), e1 = __expf(-2.f*tc1);
        float t0 = (1.f-e0)/(1.f+e0), t1 = (1.f-e1)/(1.f+e1);
        h0f += z0*(t0 - h0f);
        h1f += z1*(t1 - h1f);
        if (wlead) {
            s_h[nb]     = (_Float16)h0f;
            s_h[nb+128] = (_Float16)h1f;
            if (L == 0) {
                __half* hc = h0chunk + ((size_t)b*CH + tl)*HID;
                hc[nb]     = __float2half(h0f);
                hc[nb+128] = __float2half(h1f);
            }
        }
        pj0 = pj0N; pj1 = pj1N; pj2 = pj2N;
        __syncthreads();
    }

    if (wlead) {
        hstate[(size_t)(L*NB + b)*HID + nb]       = h0f;
        hstate[(size_t)(L*NB + b)*HID + nb + 128] = h1f;
    }

    if (L == 1 && c == NCH-1) {
        if (wlead) { s_head[nb] = h0f; s_head[nb+128] = h1f; }
        __syncthreads();
        if (tid < 64) {
            float p0 = 0.f, p1 = 0.f;
#pragma unroll
            for (int m = 0; m < 4; ++m) {
                float hv2 = s_head[tid + 64*m];
                p0 += hv2 * Wfc[(tid+64*m)*2+0];
                p1 += hv2 * Wfc[(tid+64*m)*2+1];
            }
#pragma unroll
            for (int d = 1; d < 64; d <<= 1) { p0 += __shfl_xor(p0, d); p1 += __shfl_xor(p1, d); }
            if (tid == 0) { out[b*2+0] = p0 + bfc[0]; out[b*2+1] = p1 + bfc[1]; }
        }
    }
}

// ---------------- host ----------------
extern "C" void kernel_launch(void* const* d_in, const int* in_sizes, int n_in,
                              void* d_out, int out_size, void* d_ws, size_t ws_size,
                              hipStream_t stream) {
    const int*   tokens = (const int*)  d_in[0];
    const float* emb    = (const float*)d_in[1];
    const float* Wr     = (const float*)d_in[2];
    const float* br     = (const float*)d_in[3];
    const float* Wz     = (const float*)d_in[4];
    const float* bz     = (const float*)d_in[5];
    const float* Wh     = (const float*)d_in[6];
    const float* bh     = (const float*)d_in[7];
    const float* Wfc    = (const float*)d_in[8];
    const float* bfc    = (const float*)d_in[9];
    float* out = (float*)d_out;

    char* ws = (char*)d_ws;
    uint32_t* wpack  = (uint32_t*)(ws + 0);               //   786,432 B
    __half*   wxt    = (__half*)(ws + (1u<<20));          //   786,432 B
    __half*   embf16 = (__half*)(ws + (2u<<20));          // 16,384,000 B
    __half*   proj0  = (__half*)(ws + 18874368u);         // 25,165,824 B
    __half*   proj1  = (__half*)(ws + 44040192u);         // 25,165,824 B
    __half*   h0chunk= (__half*)(ws + 69206016u);         //  8,388,608 B
    float*    hstate = (float*)(ws + 77594624u);          //    131,072 B
    float*    biasv  = (float*)(ws + 77725696u);          //      6,144 B

    prep_kernel<<<2048, 256, 0, stream>>>(Wr, Wz, Wh, emb, br, bz, bh, wpack, wxt, embf16, biasv);

    dim3 ggrid(128, 12, 2);
    for (int c = 0; c <= NCH; ++c) {
        int cc0 = (c < NCH) ? c : -1;
        int cc1 = c - 1;
        gemm_proj<<<ggrid, 256, 0, stream>>>(tokens, embf16, h0chunk, wxt, biasv, proj0, proj1, cc0, cc1);
        rec_fused<<<128, 512, 0, stream>>>(wpack, proj0, proj1, h0chunk, hstate, Wfc, bfc, out, cc0, cc1);
    }
}